// Round 11
// baseline (3077.166 us; speedup 1.0000x reference)
//
#include <hip/hip_runtime.h>
#include <math.h>

#define DEV __device__ __forceinline__

typedef float v2f __attribute__((ext_vector_type(2)));

// Exact (numpy-matching) squared distance: rn each op, association ((x+y)+z),
// NO fma contraction — required so discrete decisions (FPS argmax, ball
// membership) match the reference bit-for-bit.
DEV float d2_exact(float ax, float ay, float az, float bx, float by, float bz) {
  float dx = __fsub_rn(ax, bx);
  float dy = __fsub_rn(ay, by);
  float dz = __fsub_rn(az, bz);
  return __fadd_rn(__fadd_rn(__fmul_rn(dx, dx), __fmul_rn(dy, dy)),
                   __fmul_rn(dz, dz));
}

DEV float uni(float f) {  // wave-uniform value -> SGPR
  return __int_as_float(__builtin_amdgcn_readfirstlane(__float_as_int(f)));
}

// DPP-shifted copy of v with -inf identity for invalid/masked lanes.
template <int CTRL, int RM>
DEV float dppmax_mv(float v) {
  int s = __builtin_amdgcn_update_dpp((int)0xFF800000u, __float_as_int(v), CTRL,
                                      RM, 0xf, false);
  return __int_as_float(s);
}

// Cross-wave exchange record, double-buffered (one barrier per step).
// key = (d2_bits << 32) | ~idx — d2 >= 0 so float bits are order-monotonic;
// ~idx makes u64-max prefer the SMALLEST index on ties (jnp.argmax
// first-index semantics; per-wave index ranges are disjoint so keys are
// unique and the key-max uniquely selects a position).
// pos[sb][wv] carries the winning point's coordinates so the post-barrier
// combine needs NO second dependent LDS round trip.
template <int W>
struct __align__(16) FpsPartT {
  unsigned long long key[2][W];
  float4 pos[2][W];
};

// ---------------------------------------------------------------------------
// Multi-wave FPS core, NT threads (NT/64 waves), PPT points per thread.
// Per-thread state = 2*PPT v2f values; keep PPT <= 16 (PPT>=32 is demoted to
// scratch by the compiler — R5/R6/R8/R9: VGPR pinned ~132, 1.7-2.5x loss).
// fps1 uses NT=512 (8 waves, 2/SIMD): the two same-phase waves on each SIMD
// have independent data, so their dependent-chain stalls (DPP stages, LDS
// trips, bmax chain) interleave — fills the ~45% VALU idle measured at
// 1 wave/SIMD. Exchange widens to NT/64 slots (tree-combined in registers).
// Main loop is VMEM-free (sel staged in LDS; q dumped after the loop).
// ---------------------------------------------------------------------------
template <int PPT, int NT>
DEV void fps_core(const float* __restrict__ p, int stride, int S,
                  float* __restrict__ q, float* __restrict__ px,
                  float* __restrict__ py, float* __restrict__ pz,
                  int* __restrict__ sel, FpsPartT<NT / 64>* part) {
#pragma clang fp contract(off)
  constexpr int N = PPT * NT;
  constexpr int NP = PPT / 2;
  constexpr int W = NT / 64;
  const int tid = threadIdx.x;
  const int lane = tid & 63, wv = tid >> 6;
  const int base = tid * PPT;

  for (int n = tid; n < N; n += NT) {
    px[n] = p[(size_t)n * stride + 0];
    py[n] = p[(size_t)n * stride + 1];
    pz[n] = p[(size_t)n * stride + 2];
  }
  if (tid == 0) sel[0] = 0;
  __syncthreads();

  v2f mx2[NP], my2[NP], mz2[NP], md2[NP];
#pragma unroll
  for (int j = 0; j < NP; ++j) {
    int n = base + 2 * j;  // contiguous ownership: lane order == index order
    mx2[j] = (v2f){px[n], px[n + 1]};
    my2[j] = (v2f){py[n], py[n + 1]};
    mz2[j] = (v2f){pz[n], pz[n + 1]};
    md2[j] = (v2f){INFINITY, INFINITY};
  }

  float lx = uni(px[0]), ly = uni(py[0]), lz = uni(pz[0]);

  for (int s = 1; s < S; ++s) {
    // --- packed min-dist update, VALUE-max only (no index chain) ---
    v2f cx2 = (v2f){lx, lx};
    v2f cy2 = (v2f){ly, ly};
    v2f cz2 = (v2f){lz, lz};
    v2f bmax = (v2f){-INFINITY, -INFINITY};
#pragma unroll
    for (int j = 0; j < NP; ++j) {
      v2f dx = mx2[j] - cx2;
      v2f dy = my2[j] - cy2;
      v2f dz = mz2[j] - cz2;
      v2f xx = dx * dx;
      v2f yy = dy * dy;
      v2f zz = dz * dz;
      v2f ss = (xx + yy) + zz;  // exact ((xx+yy)+zz), contract(off)
      v2f m = __builtin_elementwise_min(md2[j], ss);
      md2[j] = m;
      bmax = __builtin_elementwise_max(bmax, m);
    }
    float bv = fmaxf(bmax.x, bmax.y);

    // --- wave value-max via DPP (result in lane 63) ---
    float m0 = bv;
    m0 = fmaxf(m0, dppmax_mv<0x111, 0xf>(m0));  // row_shr:1
    m0 = fmaxf(m0, dppmax_mv<0x112, 0xf>(m0));  // row_shr:2
    m0 = fmaxf(m0, dppmax_mv<0x114, 0xf>(m0));  // row_shr:4
    m0 = fmaxf(m0, dppmax_mv<0x118, 0xf>(m0));  // row_shr:8
    m0 = fmaxf(m0, dppmax_mv<0x142, 0xa>(m0));  // row_bcast:15 rows 1,3
    m0 = fmaxf(m0, dppmax_mv<0x143, 0xc>(m0));  // row_bcast:31 rows 2,3

    // --- first-index recovery scan (concurrent with the DPP chain) ---
    int bk = 0;
#pragma unroll
    for (int j = NP - 1; j >= 0; --j) {
      if (md2[j].y == bv) bk = 2 * j + 1;
      if (md2[j].x == bv) bk = 2 * j;
    }
    int bi = base + bk;

    float vmax =
        __int_as_float(__builtin_amdgcn_readlane(__float_as_int(m0), 63));
    // first lane holding the max -> smallest owned index within the wave
    unsigned long long mk = __ballot(bv == vmax);
    int src = __ffsll(mk) - 1;
    int wi = __builtin_amdgcn_readlane(bi, src);

    // --- wave-uniform winner-pos read: broadcast address, conflict-free ---
    float wx = px[wi], wy = py[wi], wz = pz[wi];

    // --- publish wave {key,pos}, barrier, tree-combine in registers ---
    const int sb = s & 1;
    if (lane == 0) {
      part->key[sb][wv] =
          ((unsigned long long)(unsigned int)__float_as_int(vmax) << 32) |
          (unsigned int)~wi;
      part->pos[sb][wv] = make_float4(wx, wy, wz, 0.f);
    }
    __syncthreads();

    unsigned long long k[W];
    float kx[W], ky[W], kz[W];
#pragma unroll
    for (int w = 0; w < W; ++w) {  // fully unrolled -> static idx -> SSA
      k[w] = part->key[sb][w];
      float4 pp = part->pos[sb][w];
      kx[w] = pp.x;
      ky[w] = pp.y;
      kz[w] = pp.z;
    }
#pragma unroll
    for (int st = W / 2; st >= 1; st >>= 1) {
#pragma unroll
      for (int i = 0; i < st; ++i) {
        bool c = k[i + st] > k[i];  // keys unique -> strict > is exact
        k[i] = c ? k[i + st] : k[i];
        kx[i] = c ? kx[i + st] : kx[i];
        ky[i] = c ? ky[i + st] : ky[i];
        kz[i] = c ? kz[i + st] : kz[i];
      }
    }
    lx = kx[0];
    ly = ky[0];
    lz = kz[0];

    // stage winner index for the final q dump (LDS only; no vmem in loop)
    if (tid == 0) sel[s] = (int)~(unsigned int)k[0];
  }

  // --- dump q from LDS once, off the serial chain ---
  __syncthreads();
  for (int s = tid; s < S; s += NT) {
    int i = sel[s];
    q[s * 3 + 0] = px[i];
    q[s * 3 + 1] = py[i];
    q[s * 3 + 2] = pz[i];
  }
}

// ---------------------------------------------------------------------------
// FPS layer 1: x [4,4096,6] -> qpos1 [4,2048,3]. One block per batch,
// 512 threads = 8 waves (2/SIMD) x PPT=8.
// ---------------------------------------------------------------------------
__global__ __launch_bounds__(512) void fps1_kernel(const float* __restrict__ x,
                                                   float* __restrict__ qpos1) {
  __shared__ __align__(16) float smem[4096 * 3 + 2048 + 96];
  const float* p = x + (size_t)blockIdx.x * 4096 * 6;
  float* q = qpos1 + (size_t)blockIdx.x * 2048 * 3;
  fps_core<8, 512>(p, 6, 2048, q, smem, smem + 4096, smem + 8192,
                   (int*)(smem + 12288),
                   (FpsPartT<8>*)(smem + 12288 + 2048));
}

// ---------------------------------------------------------------------------
// Dense MLP layer, one neighbor per lane; weights via wave-uniform loads.
// w is [CIN, WSTRIDE] row-major, columns [0, COUT). relu fused.
// ---------------------------------------------------------------------------
template <int CIN, int COUT, int WSTRIDE>
DEV void mlp_layer(const float* __restrict__ hin, float* __restrict__ hout,
                   const float* __restrict__ w, const float* __restrict__ b) {
#pragma unroll
  for (int j = 0; j < COUT; j += 4) {
    float4 acc = *(const float4*)(b + j);
#pragma unroll
    for (int c = 0; c < CIN; ++c) {
      float4 wvec = *(const float4*)(w + (size_t)c * WSTRIDE + j);
      acc.x = fmaf(hin[c], wvec.x, acc.x);
      acc.y = fmaf(hin[c], wvec.y, acc.y);
      acc.z = fmaf(hin[c], wvec.z, acc.z);
      acc.w = fmaf(hin[c], wvec.w, acc.w);
    }
    hout[j + 0] = fmaxf(acc.x, 0.f);
    hout[j + 1] = fmaxf(acc.y, 0.f);
    hout[j + 2] = fmaxf(acc.z, 0.f);
    hout[j + 3] = fmaxf(acc.w, 0.f);
  }
}

// Folding max-pool across 64 lanes for 64 channels held per-lane in v[64].
// After the fold, lane l holds the cross-lane max of channel l in v[0].
DEV void pool64(float* v, int lane) {
#pragma unroll
  for (int o = 32; o >= 1; o >>= 1) {
    bool bit = (lane & o) != 0;
#pragma unroll
    for (int j = 0; j < o; ++j) {
      float send = bit ? v[j] : v[j + o];
      float keep = bit ? v[j + o] : v[j];
      float recv = __shfl_xor(send, o, 64);
      v[j] = fmaxf(keep, recv);
    }
  }
}

// Ordered ball query: first (up to) 64 lowest-index points with d2 <= r2.
DEV int ball_query_wave(const float* __restrict__ pos, int stride, int n_pts,
                        float qx, float qy, float qz, float r2, int lane,
                        int* __restrict__ nls, bool& valid) {
  int cnt = 0;
  for (int base = 0; base < n_pts && cnt < 64; base += 64) {
    int n = base + lane;
    float d2 = d2_exact(pos[(size_t)n * stride + 0], pos[(size_t)n * stride + 1],
                        pos[(size_t)n * stride + 2], qx, qy, qz);
    bool in = (d2 <= r2);
    unsigned long long m = __ballot(in);
    int slot = cnt + (int)__popcll(m & ((1ull << lane) - 1ull));
    if (in && slot < 64) nls[slot] = n;
    cnt += (int)__popcll(m);
  }
  int kcnt = cnt < 64 ? cnt : 64;
  valid = lane < kcnt;
  return valid ? nls[lane] : 0;
}

// ---------------------------------------------------------------------------
// Fused dispatch: blocks 0..3 = FPS layer 2 (qpos1 [4,2048,3] -> qpos2
// [4,512,3], 4-wave PPT=8 — proven config); blocks 4..2051 = SetConv layer 1
// (independent of fps2, both consume fps1 output). fps2 blocks first.
// ---------------------------------------------------------------------------
__global__ __launch_bounds__(256) void sc1_fps2_kernel(
    const float* __restrict__ x, const float* __restrict__ qpos1,
    const float* __restrict__ wa, const float* __restrict__ ba,
    const float* __restrict__ wb, const float* __restrict__ bb,
    const float* __restrict__ wc, const float* __restrict__ bc,
    float* __restrict__ feat1, float* __restrict__ qpos2) {
  __shared__ __align__(16) float smem[2048 * 3 + 48 + 512];

  if (blockIdx.x < 4) {
    const float* p = qpos1 + (size_t)blockIdx.x * 2048 * 3;
    float* q = qpos2 + (size_t)blockIdx.x * 512 * 3;
    fps_core<8, 256>(p, 3, 512, q, smem, smem + 2048, smem + 4096,
                     (int*)(smem + 6144 + 48),
                     (FpsPartT<4>*)(smem + 6144));
    return;
  }

  // ---- setconv1: MLP 6->32->32->64, r^2=0.25, one wave per query ----
  int* nls = (int*)smem;  // [4][64]
  const int lane = threadIdx.x & 63, wv = threadIdx.x >> 6;
  const int qi = (blockIdx.x - 4) * 4 + wv;  // 0..8191
  const int b = qi >> 11;
  const float* xb = x + (size_t)b * 4096 * 6;
  const float qx = qpos1[qi * 3 + 0], qy = qpos1[qi * 3 + 1],
              qz = qpos1[qi * 3 + 2];

  bool valid;
  int nb =
      ball_query_wave(xb, 6, 4096, qx, qy, qz, 0.25f, lane, nls + wv * 64, valid);

  const float* xr = xb + (size_t)nb * 6;
  float h0[6];
  h0[0] = xr[3];
  h0[1] = xr[4];
  h0[2] = xr[5];
  h0[3] = xr[0] - qx;
  h0[4] = xr[1] - qy;
  h0[5] = xr[2] - qz;

  float h1[32];
  mlp_layer<6, 32, 32>(h0, h1, wa, ba);
  float h2[32];
  mlp_layer<32, 32, 32>(h1, h2, wb, bb);
  float h3[64];
  mlp_layer<32, 64, 64>(h2, h3, wc, bc);

  if (!valid) {
#pragma unroll
    for (int j = 0; j < 64; ++j) h3[j] = -INFINITY;
  }
  pool64(h3, lane);
  feat1[(size_t)qi * 64 + lane] = h3[0];  // lane l holds channel l
}

// ---------------------------------------------------------------------------
// SetConv layer 2: queries [4,512], points qpos1 [4,2048,3] + feat1
// [4,2048,64]. MLP 67->64->64->128, r^2=1.0. Also fills the batch output.
// ---------------------------------------------------------------------------
__global__ __launch_bounds__(256) void setconv2_kernel(
    const float* __restrict__ feat1, const float* __restrict__ qpos1,
    const float* __restrict__ qpos2, const float* __restrict__ wa,
    const float* __restrict__ ba, const float* __restrict__ wb,
    const float* __restrict__ bb, const float* __restrict__ wc,
    const float* __restrict__ bc, float* __restrict__ feat_out,
    float* __restrict__ batch) {
  __shared__ int nls[4][64];
  const int lane = threadIdx.x & 63, wv = threadIdx.x >> 6;
  const int qi = blockIdx.x * 4 + wv;  // 0..2047
  const int b = qi >> 9;
  const float* pb = qpos1 + (size_t)b * 2048 * 3;
  const float* fb = feat1 + (size_t)b * 2048 * 64;
  const float qx = qpos2[qi * 3 + 0], qy = qpos2[qi * 3 + 1],
              qz = qpos2[qi * 3 + 2];

  if (threadIdx.x < 4) {
    int j = blockIdx.x * 4 + threadIdx.x;
    batch[j] = (float)(j >> 9);  // repeat(arange(4), 512)
  }

  bool valid;
  int nb = ball_query_wave(pb, 3, 2048, qx, qy, qz, 1.0f, lane, nls[wv], valid);

  float h0[67];
  {
    const float* fr = fb + (size_t)nb * 64;
#pragma unroll
    for (int c = 0; c < 64; c += 4) {
      float4 v = *(const float4*)(fr + c);
      h0[c + 0] = v.x;
      h0[c + 1] = v.y;
      h0[c + 2] = v.z;
      h0[c + 3] = v.w;
    }
    const float* pr = pb + (size_t)nb * 3;
    h0[64] = pr[0] - qx;
    h0[65] = pr[1] - qy;
    h0[66] = pr[2] - qz;
  }

  float h1[64];
  mlp_layer<67, 64, 64>(h0, h1, wa, ba);
  float h2[64];
  mlp_layer<64, 64, 64>(h1, h2, wb, bb);

#pragma unroll 1
  for (int half = 0; half < 2; ++half) {
    float h3[64];
    mlp_layer<64, 64, 128>(h2, h3, wc + half * 64, bc + half * 64);
    if (!valid) {
#pragma unroll
      for (int j = 0; j < 64; ++j) h3[j] = -INFINITY;
    }
    pool64(h3, lane);
    feat_out[(size_t)qi * 128 + half * 64 + lane] = h3[0];
  }
}

// ---------------------------------------------------------------------------
extern "C" void kernel_launch(void* const* d_in, const int* in_sizes, int n_in,
                              void* d_out, int out_size, void* d_ws,
                              size_t ws_size, hipStream_t stream) {
  const float* x   = (const float*)d_in[0];
  const float* w1a = (const float*)d_in[1];
  const float* b1a = (const float*)d_in[2];
  const float* w1b = (const float*)d_in[3];
  const float* b1b = (const float*)d_in[4];
  const float* w1c = (const float*)d_in[5];
  const float* b1c = (const float*)d_in[6];
  const float* w2a = (const float*)d_in[7];
  const float* b2a = (const float*)d_in[8];
  const float* w2b = (const float*)d_in[9];
  const float* b2b = (const float*)d_in[10];
  const float* w2c = (const float*)d_in[11];
  const float* b2c = (const float*)d_in[12];

  float* out = (float*)d_out;
  float* qpos1 = (float*)d_ws;                  // 4*2048*3 floats
  float* feat1 = qpos1 + 4 * 2048 * 3;          // 4*2048*64 floats
  float* feat2 = out;                           // 2048*128
  float* qpos2 = out + 2048 * 128;              // 2048*3
  float* batch = out + 2048 * 128 + 2048 * 3;   // 2048

  fps1_kernel<<<4, 512, 0, stream>>>(x, qpos1);
  sc1_fps2_kernel<<<2052, 256, 0, stream>>>(x, qpos1, w1a, b1a, w1b, b1b, w1c,
                                            b1c, feat1, qpos2);
  setconv2_kernel<<<512, 256, 0, stream>>>(feat1, qpos1, qpos2, w2a, b2a, w2b,
                                           b2b, w2c, b2c, feat2, batch);
}

// Round 12
// 1637.198 us; speedup vs baseline: 1.8795x; 1.8795x over previous
//
#include <hip/hip_runtime.h>
#include <math.h>

#define DEV __device__ __forceinline__

typedef float v2f __attribute__((ext_vector_type(2)));

// Exact (numpy-matching) squared distance: rn each op, association ((x+y)+z),
// NO fma contraction — required so discrete decisions (FPS argmax, ball
// membership) match the reference bit-for-bit.
DEV float d2_exact(float ax, float ay, float az, float bx, float by, float bz) {
  float dx = __fsub_rn(ax, bx);
  float dy = __fsub_rn(ay, by);
  float dz = __fsub_rn(az, bz);
  return __fadd_rn(__fadd_rn(__fmul_rn(dx, dx), __fmul_rn(dy, dy)),
                   __fmul_rn(dz, dz));
}

DEV float uni(float f) {  // wave-uniform value -> SGPR
  return __int_as_float(__builtin_amdgcn_readfirstlane(__float_as_int(f)));
}

// DPP-shifted copy of v with -inf identity for invalid/masked lanes.
template <int CTRL, int RM>
DEV float dppmax_mv(float v) {
  int s = __builtin_amdgcn_update_dpp((int)0xFF800000u, __float_as_int(v), CTRL,
                                      RM, 0xf, false);
  return __int_as_float(s);
}

// Cross-wave exchange record, double-buffered (one barrier per step).
// key = (d2_bits << 32) | ~idx — d2 >= 0 so float bits are order-monotonic;
// ~idx makes u64-max prefer the SMALLEST index on ties (jnp.argmax
// first-index semantics; per-wave index ranges are disjoint so keys are
// unique and the key-max uniquely selects a position).
// pos[sb][wv] carries the winning point's coordinates so the post-barrier
// combine needs NO second dependent LDS round trip.
struct __align__(16) FpsPart {
  unsigned long long key[2][4];
  float4 pos[2][4];
};

// ---------------------------------------------------------------------------
// 4-wave FPS core, PPT=16/8 — the measured optimum of this session's search:
//  - PPT>=32 (fewer waves, more state): compiler demotes the loop state to
//    scratch (R5/R6/R8/R9: VGPR pinned ~132, 1.7-2.5x loss) regardless of
//    array vs named-scalar representation or launch-bounds hints.
//  - 8 waves x PPT=8 (more waves, less state): barrier arrival/wake skew +
//    wider exchange dominate, 2.2x loss (R11). Waves are phase-locked by the
//    per-step barrier, so extra waves cannot fill dependent-chain stalls.
// Per step: packed v_pk_* min-dist update accumulating only the VALUE max
// (short dep chain); first-index recovered by a descending equality scan
// over register-resident md2 that issues inside the DPP value-reduce's
// stall slots. Then ballot first-lane; lane0 publishes {key,pos}; single
// barrier; key-max + pos select tree in registers. Main loop is VMEM-free
// (sel staged in LDS; q dumped after the loop).
// ---------------------------------------------------------------------------
template <int PPT>
DEV void fps_core(const float* __restrict__ p, int stride, int S,
                  float* __restrict__ q, float* __restrict__ px,
                  float* __restrict__ py, float* __restrict__ pz,
                  int* __restrict__ sel, FpsPart* part) {
#pragma clang fp contract(off)
  constexpr int N = PPT * 256;
  constexpr int NP = PPT / 2;
  const int tid = threadIdx.x;
  const int lane = tid & 63, wv = tid >> 6;
  const int base = tid * PPT;

  for (int n = tid; n < N; n += 256) {
    px[n] = p[(size_t)n * stride + 0];
    py[n] = p[(size_t)n * stride + 1];
    pz[n] = p[(size_t)n * stride + 2];
  }
  if (tid == 0) sel[0] = 0;
  __syncthreads();

  v2f mx2[NP], my2[NP], mz2[NP], md2[NP];
#pragma unroll
  for (int j = 0; j < NP; ++j) {
    int n = base + 2 * j;  // contiguous ownership: lane order == index order
    mx2[j] = (v2f){px[n], px[n + 1]};
    my2[j] = (v2f){py[n], py[n + 1]};
    mz2[j] = (v2f){pz[n], pz[n + 1]};
    md2[j] = (v2f){INFINITY, INFINITY};
  }

  float lx = uni(px[0]), ly = uni(py[0]), lz = uni(pz[0]);

  for (int s = 1; s < S; ++s) {
    // --- packed min-dist update, VALUE-max only (no index chain) ---
    v2f cx2 = (v2f){lx, lx};
    v2f cy2 = (v2f){ly, ly};
    v2f cz2 = (v2f){lz, lz};
    v2f bmax = (v2f){-INFINITY, -INFINITY};
#pragma unroll
    for (int j = 0; j < NP; ++j) {
      v2f dx = mx2[j] - cx2;
      v2f dy = my2[j] - cy2;
      v2f dz = mz2[j] - cz2;
      v2f xx = dx * dx;
      v2f yy = dy * dy;
      v2f zz = dz * dz;
      v2f ss = (xx + yy) + zz;  // exact ((xx+yy)+zz), contract(off)
      v2f m = __builtin_elementwise_min(md2[j], ss);
      md2[j] = m;
      bmax = __builtin_elementwise_max(bmax, m);
    }
    float bv = fmaxf(bmax.x, bmax.y);

    // --- wave value-max via DPP (result in lane 63) ---
    float m0 = bv;
    m0 = fmaxf(m0, dppmax_mv<0x111, 0xf>(m0));  // row_shr:1
    m0 = fmaxf(m0, dppmax_mv<0x112, 0xf>(m0));  // row_shr:2
    m0 = fmaxf(m0, dppmax_mv<0x114, 0xf>(m0));  // row_shr:4
    m0 = fmaxf(m0, dppmax_mv<0x118, 0xf>(m0));  // row_shr:8
    m0 = fmaxf(m0, dppmax_mv<0x142, 0xa>(m0));  // row_bcast:15 rows 1,3
    m0 = fmaxf(m0, dppmax_mv<0x143, 0xc>(m0));  // row_bcast:31 rows 2,3

    // --- first-index recovery scan (concurrent with the DPP chain) ---
    int bk = 0;
#pragma unroll
    for (int j = NP - 1; j >= 0; --j) {
      if (md2[j].y == bv) bk = 2 * j + 1;
      if (md2[j].x == bv) bk = 2 * j;
    }
    int bi = base + bk;

    float vmax =
        __int_as_float(__builtin_amdgcn_readlane(__float_as_int(m0), 63));
    // first lane holding the max -> smallest owned index within the wave
    unsigned long long mk = __ballot(bv == vmax);
    int src = __ffsll(mk) - 1;
    int wi = __builtin_amdgcn_readlane(bi, src);

    // --- wave-uniform winner-pos read: broadcast address, conflict-free ---
    float wx = px[wi], wy = py[wi], wz = pz[wi];

    // --- publish wave {key,pos}, barrier, combine in registers ---
    const int sb = s & 1;
    if (lane == 0) {
      part->key[sb][wv] =
          ((unsigned long long)(unsigned int)__float_as_int(vmax) << 32) |
          (unsigned int)~wi;
      part->pos[sb][wv] = make_float4(wx, wy, wz, 0.f);
    }
    __syncthreads();

    ulonglong2 k01 = *(const ulonglong2*)&part->key[sb][0];
    ulonglong2 k23 = *(const ulonglong2*)&part->key[sb][2];
    float4 p0 = part->pos[sb][0];
    float4 p1 = part->pos[sb][1];
    float4 p2 = part->pos[sb][2];
    float4 p3 = part->pos[sb][3];

    bool c01 = k01.x >= k01.y;
    unsigned long long kA = c01 ? k01.x : k01.y;
    float ax = c01 ? p0.x : p1.x;
    float ay = c01 ? p0.y : p1.y;
    float az = c01 ? p0.z : p1.z;
    bool c23 = k23.x >= k23.y;
    unsigned long long kB = c23 ? k23.x : k23.y;
    float bx = c23 ? p2.x : p3.x;
    float by = c23 ? p2.y : p3.y;
    float bz = c23 ? p2.z : p3.z;
    bool cab = kA >= kB;
    unsigned long long kb = cab ? kA : kB;
    lx = cab ? ax : bx;
    ly = cab ? ay : by;
    lz = cab ? az : bz;

    // stage winner index for the final q dump (LDS only; no vmem in loop)
    if (tid == 0) sel[s] = (int)~(unsigned int)kb;
  }

  // --- dump q from LDS once, off the serial chain ---
  __syncthreads();
  for (int s = tid; s < S; s += 256) {
    int i = sel[s];
    q[s * 3 + 0] = px[i];
    q[s * 3 + 1] = py[i];
    q[s * 3 + 2] = pz[i];
  }
}

// ---------------------------------------------------------------------------
// FPS layer 1: x [4,4096,6] -> qpos1 [4,2048,3]. One block per batch.
// ---------------------------------------------------------------------------
__global__ __launch_bounds__(256) void fps1_kernel(const float* __restrict__ x,
                                                   float* __restrict__ qpos1) {
  __shared__ __align__(16) float smem[4096 * 3 + 48 + 2048];
  const float* p = x + (size_t)blockIdx.x * 4096 * 6;
  float* q = qpos1 + (size_t)blockIdx.x * 2048 * 3;
  fps_core<16>(p, 6, 2048, q, smem, smem + 4096, smem + 8192,
               (int*)(smem + 12288 + 48), (FpsPart*)(smem + 12288));
}

// ---------------------------------------------------------------------------
// Dense MLP layer, one neighbor per lane; weights via wave-uniform loads.
// w is [CIN, WSTRIDE] row-major, columns [0, COUT). relu fused.
// ---------------------------------------------------------------------------
template <int CIN, int COUT, int WSTRIDE>
DEV void mlp_layer(const float* __restrict__ hin, float* __restrict__ hout,
                   const float* __restrict__ w, const float* __restrict__ b) {
#pragma unroll
  for (int j = 0; j < COUT; j += 4) {
    float4 acc = *(const float4*)(b + j);
#pragma unroll
    for (int c = 0; c < CIN; ++c) {
      float4 wvec = *(const float4*)(w + (size_t)c * WSTRIDE + j);
      acc.x = fmaf(hin[c], wvec.x, acc.x);
      acc.y = fmaf(hin[c], wvec.y, acc.y);
      acc.z = fmaf(hin[c], wvec.z, acc.z);
      acc.w = fmaf(hin[c], wvec.w, acc.w);
    }
    hout[j + 0] = fmaxf(acc.x, 0.f);
    hout[j + 1] = fmaxf(acc.y, 0.f);
    hout[j + 2] = fmaxf(acc.z, 0.f);
    hout[j + 3] = fmaxf(acc.w, 0.f);
  }
}

// Folding max-pool across 64 lanes for 64 channels held per-lane in v[64].
// After the fold, lane l holds the cross-lane max of channel l in v[0].
DEV void pool64(float* v, int lane) {
#pragma unroll
  for (int o = 32; o >= 1; o >>= 1) {
    bool bit = (lane & o) != 0;
#pragma unroll
    for (int j = 0; j < o; ++j) {
      float send = bit ? v[j] : v[j + o];
      float keep = bit ? v[j + o] : v[j];
      float recv = __shfl_xor(send, o, 64);
      v[j] = fmaxf(keep, recv);
    }
  }
}

// Ordered ball query: first (up to) 64 lowest-index points with d2 <= r2.
DEV int ball_query_wave(const float* __restrict__ pos, int stride, int n_pts,
                        float qx, float qy, float qz, float r2, int lane,
                        int* __restrict__ nls, bool& valid) {
  int cnt = 0;
  for (int base = 0; base < n_pts && cnt < 64; base += 64) {
    int n = base + lane;
    float d2 = d2_exact(pos[(size_t)n * stride + 0], pos[(size_t)n * stride + 1],
                        pos[(size_t)n * stride + 2], qx, qy, qz);
    bool in = (d2 <= r2);
    unsigned long long m = __ballot(in);
    int slot = cnt + (int)__popcll(m & ((1ull << lane) - 1ull));
    if (in && slot < 64) nls[slot] = n;
    cnt += (int)__popcll(m);
  }
  int kcnt = cnt < 64 ? cnt : 64;
  valid = lane < kcnt;
  return valid ? nls[lane] : 0;
}

// ---------------------------------------------------------------------------
// Fused dispatch: blocks 0..3 = FPS layer 2 (qpos1 [4,2048,3] -> qpos2
// [4,512,3]); blocks 4..2051 = SetConv layer 1 (independent of fps2, both
// consume fps1 output). fps2 blocks first so they start immediately.
// ---------------------------------------------------------------------------
__global__ __launch_bounds__(256) void sc1_fps2_kernel(
    const float* __restrict__ x, const float* __restrict__ qpos1,
    const float* __restrict__ wa, const float* __restrict__ ba,
    const float* __restrict__ wb, const float* __restrict__ bb,
    const float* __restrict__ wc, const float* __restrict__ bc,
    float* __restrict__ feat1, float* __restrict__ qpos2) {
  __shared__ __align__(16) float smem[2048 * 3 + 48 + 512];

  if (blockIdx.x < 4) {
    const float* p = qpos1 + (size_t)blockIdx.x * 2048 * 3;
    float* q = qpos2 + (size_t)blockIdx.x * 512 * 3;
    fps_core<8>(p, 3, 512, q, smem, smem + 2048, smem + 4096,
                (int*)(smem + 6144 + 48), (FpsPart*)(smem + 6144));
    return;
  }

  // ---- setconv1: MLP 6->32->32->64, r^2=0.25, one wave per query ----
  int* nls = (int*)smem;  // [4][64]
  const int lane = threadIdx.x & 63, wv = threadIdx.x >> 6;
  const int qi = (blockIdx.x - 4) * 4 + wv;  // 0..8191
  const int b = qi >> 11;
  const float* xb = x + (size_t)b * 4096 * 6;
  const float qx = qpos1[qi * 3 + 0], qy = qpos1[qi * 3 + 1],
              qz = qpos1[qi * 3 + 2];

  bool valid;
  int nb =
      ball_query_wave(xb, 6, 4096, qx, qy, qz, 0.25f, lane, nls + wv * 64, valid);

  const float* xr = xb + (size_t)nb * 6;
  float h0[6];
  h0[0] = xr[3];
  h0[1] = xr[4];
  h0[2] = xr[5];
  h0[3] = xr[0] - qx;
  h0[4] = xr[1] - qy;
  h0[5] = xr[2] - qz;

  float h1[32];
  mlp_layer<6, 32, 32>(h0, h1, wa, ba);
  float h2[32];
  mlp_layer<32, 32, 32>(h1, h2, wb, bb);
  float h3[64];
  mlp_layer<32, 64, 64>(h2, h3, wc, bc);

  if (!valid) {
#pragma unroll
    for (int j = 0; j < 64; ++j) h3[j] = -INFINITY;
  }
  pool64(h3, lane);
  feat1[(size_t)qi * 64 + lane] = h3[0];  // lane l holds channel l
}

// ---------------------------------------------------------------------------
// SetConv layer 2: queries [4,512], points qpos1 [4,2048,3] + feat1
// [4,2048,64]. MLP 67->64->64->128, r^2=1.0. Also fills the batch output.
// ---------------------------------------------------------------------------
__global__ __launch_bounds__(256) void setconv2_kernel(
    const float* __restrict__ feat1, const float* __restrict__ qpos1,
    const float* __restrict__ qpos2, const float* __restrict__ wa,
    const float* __restrict__ ba, const float* __restrict__ wb,
    const float* __restrict__ bb, const float* __restrict__ wc,
    const float* __restrict__ bc, float* __restrict__ feat_out,
    float* __restrict__ batch) {
  __shared__ int nls[4][64];
  const int lane = threadIdx.x & 63, wv = threadIdx.x >> 6;
  const int qi = blockIdx.x * 4 + wv;  // 0..2047
  const int b = qi >> 9;
  const float* pb = qpos1 + (size_t)b * 2048 * 3;
  const float* fb = feat1 + (size_t)b * 2048 * 64;
  const float qx = qpos2[qi * 3 + 0], qy = qpos2[qi * 3 + 1],
              qz = qpos2[qi * 3 + 2];

  if (threadIdx.x < 4) {
    int j = blockIdx.x * 4 + threadIdx.x;
    batch[j] = (float)(j >> 9);  // repeat(arange(4), 512)
  }

  bool valid;
  int nb = ball_query_wave(pb, 3, 2048, qx, qy, qz, 1.0f, lane, nls[wv], valid);

  float h0[67];
  {
    const float* fr = fb + (size_t)nb * 64;
#pragma unroll
    for (int c = 0; c < 64; c += 4) {
      float4 v = *(const float4*)(fr + c);
      h0[c + 0] = v.x;
      h0[c + 1] = v.y;
      h0[c + 2] = v.z;
      h0[c + 3] = v.w;
    }
    const float* pr = pb + (size_t)nb * 3;
    h0[64] = pr[0] - qx;
    h0[65] = pr[1] - qy;
    h0[66] = pr[2] - qz;
  }

  float h1[64];
  mlp_layer<67, 64, 64>(h0, h1, wa, ba);
  float h2[64];
  mlp_layer<64, 64, 64>(h1, h2, wb, bb);

#pragma unroll 1
  for (int half = 0; half < 2; ++half) {
    float h3[64];
    mlp_layer<64, 64, 128>(h2, h3, wc + half * 64, bc + half * 64);
    if (!valid) {
#pragma unroll
      for (int j = 0; j < 64; ++j) h3[j] = -INFINITY;
    }
    pool64(h3, lane);
    feat_out[(size_t)qi * 128 + half * 64 + lane] = h3[0];
  }
}

// ---------------------------------------------------------------------------
extern "C" void kernel_launch(void* const* d_in, const int* in_sizes, int n_in,
                              void* d_out, int out_size, void* d_ws,
                              size_t ws_size, hipStream_t stream) {
  const float* x   = (const float*)d_in[0];
  const float* w1a = (const float*)d_in[1];
  const float* b1a = (const float*)d_in[2];
  const float* w1b = (const float*)d_in[3];
  const float* b1b = (const float*)d_in[4];
  const float* w1c = (const float*)d_in[5];
  const float* b1c = (const float*)d_in[6];
  const float* w2a = (const float*)d_in[7];
  const float* b2a = (const float*)d_in[8];
  const float* w2b = (const float*)d_in[9];
  const float* b2b = (const float*)d_in[10];
  const float* w2c = (const float*)d_in[11];
  const float* b2c = (const float*)d_in[12];

  float* out = (float*)d_out;
  float* qpos1 = (float*)d_ws;                  // 4*2048*3 floats
  float* feat1 = qpos1 + 4 * 2048 * 3;          // 4*2048*64 floats
  float* feat2 = out;                           // 2048*128
  float* qpos2 = out + 2048 * 128;              // 2048*3
  float* batch = out + 2048 * 128 + 2048 * 3;   // 2048

  fps1_kernel<<<4, 256, 0, stream>>>(x, qpos1);
  sc1_fps2_kernel<<<2052, 256, 0, stream>>>(x, qpos1, w1a, b1a, w1b, b1b, w1c,
                                            b1c, feat1, qpos2);
  setconv2_kernel<<<512, 256, 0, stream>>>(feat1, qpos1, qpos2, w2a, b2a, w2b,
                                           b2b, w2c, b2c, feat2, batch);
}